// Round 1
// 1045.028 us; speedup vs baseline: 1.0219x; 1.0219x over previous
//
#include <hip/hip_runtime.h>

#define NBINS 15
#define NCLS  100
#define TROWS 128                 // tile rows == block threads
#define NF4   (NCLS / 4)          // 25 float4 per row
#define GRID  768                 // 3 blocks/CU (LDS-limited: 51.4 KB/block) * 256 CU

// ---------------------------------------------------------------------------
// init: zero the 45-float global histogram in d_ws (harness poisons ws 0xAA)
// ---------------------------------------------------------------------------
__global__ void ece_init_kernel(float* __restrict__ gbins) {
    int i = threadIdx.x;
    if (i < 3 * NBINS) gbins[i] = 0.0f;
}

// per-row softmax stats from a 16B-aligned row of 100 floats:
//   conf = exp(max)/sum(exp)   (no max-subtract: |x|<~7, fp32-safe)
//   ix   = first-occurrence argmax
__device__ __forceinline__ void row_stats(const float4* __restrict__ row,
                                          float& conf, int& ix)
{
    float m  = -3.402823466e+38f;
    float s0 = 0.0f, s1 = 0.0f, s2 = 0.0f, s3 = 0.0f;
    ix = 0;
    #pragma unroll
    for (int i = 0; i < NF4; ++i) {
        float4 v = row[i];
        s0 += __expf(v.x);
        s1 += __expf(v.y);
        s2 += __expf(v.z);
        s3 += __expf(v.w);
        bool g;
        g = v.x > m; ix = g ? 4 * i + 0 : ix; m = g ? v.x : m;
        g = v.y > m; ix = g ? 4 * i + 1 : ix; m = g ? v.y : m;
        g = v.z > m; ix = g ? 4 * i + 2 : ix; m = g ? v.z : m;
        g = v.w > m; ix = g ? 4 * i + 3 : ix; m = g ? v.w : m;
    }
    conf = __expf(m) / ((s0 + s1) + (s2 + s3));
}

// searchsorted-left - 1 over linspace(0,1,16): bin = #{ i in 1..15 : conf > i/15 }
__device__ __forceinline__ int bin_of(float conf) {
    int bin = 0;
    #pragma unroll
    for (int i = 1; i <= NBINS; ++i)
        bin += (conf > (float)i * (1.0f / 15.0f)) ? 1 : 0;
    return min(bin, NBINS - 1);   // safety; conf < 1 in practice
}

// ---------------------------------------------------------------------------
// main: persistent blocks grid-stride over 128-row tiles.
//   stage: tile (128 rows x 400 B = 51200 B) HBM->LDS via global_load_lds
//          width-16, fully coalesced (64 lanes x 16 B contiguous per instr).
//   compute: thread t owns row t of the tile, reads it from LDS (b128).
// 3 blocks/CU (LDS-limited) give stage/compute overlap across blocks.
// ---------------------------------------------------------------------------
__global__ __launch_bounds__(TROWS) void ece_main_kernel(
        const float* __restrict__ logits,
        const int*   __restrict__ labels,
        float*       __restrict__ gbins,
        int n_rows)
{
    __shared__ float tile[TROWS * NCLS];   // 51200 B, linear (global_load_lds dest)
    __shared__ float sb[3 * NBINS];

    const int t = threadIdx.x;
    for (int i = t; i < 3 * NBINS; i += TROWS) sb[i] = 0.0f;
    // visibility of sb init is covered by the first __syncthreads below

    const int n_tiles = n_rows / TROWS;
    for (int tl = blockIdx.x; tl < n_tiles; tl += gridDim.x) {
        // prior iteration's readers must be done before LDS is overwritten
        __syncthreads();

        const float* gsrc = logits + (size_t)tl * (TROWS * NCLS);
        #pragma unroll
        for (int k = 0; k < NF4; ++k) {
            const int idx = (k * TROWS + t) * 4;   // float index, 0..12796
            // lanes of a wave: lds dest = uniform base + lane*16, src linear
            __builtin_amdgcn_global_load_lds(
                (const __attribute__((address_space(1))) unsigned int*)(gsrc + idx),
                (__attribute__((address_space(3)))       unsigned int*)(tile + idx),
                16, 0, 0);
        }
        const int lbl = labels[(size_t)tl * TROWS + t];  // coalesced, hides latency

        // compiler emits s_waitcnt vmcnt(0) before s_barrier -> tile ready
        __syncthreads();

        float conf; int ix;
        row_stats(reinterpret_cast<const float4*>(tile + t * NCLS), conf, ix);
        const float acc = (ix == lbl) ? 1.0f : 0.0f;
        const int   bin = bin_of(conf);
        atomicAdd(&sb[bin],             1.0f);
        atomicAdd(&sb[NBINS + bin],     conf);
        atomicAdd(&sb[2 * NBINS + bin], acc);
    }

    // remainder rows (n_rows % TROWS), direct-from-global path, block 0 only
    if (blockIdx.x == 0) {
        for (int r = n_tiles * TROWS + t; r < n_rows; r += TROWS) {
            float conf; int ix;
            row_stats(reinterpret_cast<const float4*>(logits + (size_t)r * NCLS),
                      conf, ix);
            const float acc = (ix == labels[r]) ? 1.0f : 0.0f;
            const int   bin = bin_of(conf);
            atomicAdd(&sb[bin],             1.0f);
            atomicAdd(&sb[NBINS + bin],     conf);
            atomicAdd(&sb[2 * NBINS + bin], acc);
        }
    }

    __syncthreads();
    if (t < 3 * NBINS) atomicAdd(&gbins[t], sb[t]);
}

// ---------------------------------------------------------------------------
// finalize: ece = sum over nonempty bins of |conf_sum - acc_sum| / n
// (|cs/cnt - as/cnt| * cnt/n simplifies; cnt>0 => denom=cnt)
// ---------------------------------------------------------------------------
__global__ void ece_final_kernel(const float* __restrict__ gbins,
                                 float* __restrict__ out,
                                 float inv_n)
{
    int lane = threadIdx.x;
    float term = 0.0f;
    if (lane < NBINS) {
        float cnt = gbins[lane];
        if (cnt > 0.0f) {
            float cs = gbins[NBINS + lane];
            float as = gbins[2 * NBINS + lane];
            term = fabsf(cs - as) * inv_n;
        }
    }
    #pragma unroll
    for (int off = 32; off >= 1; off >>= 1)
        term += __shfl_down(term, off);
    if (lane == 0) out[0] = term;
}

extern "C" void kernel_launch(void* const* d_in, const int* in_sizes, int n_in,
                              void* d_out, int out_size, void* d_ws, size_t ws_size,
                              hipStream_t stream) {
    const float* logits = (const float*)d_in[0];
    const int*   labels = (const int*)d_in[1];
    const int    n_rows = in_sizes[1];

    float* gbins = (float*)d_ws;   // 45 floats
    float* out   = (float*)d_out;

    ece_init_kernel<<<1, 64, 0, stream>>>(gbins);

    // 768 persistent blocks x 128 threads, 3 blocks/CU (51.4 KB LDS each).
    // Each block grid-strides over 128-row tiles: coalesced async stage into
    // LDS, then thread-per-row compute; inter-block TLP overlaps the phases.
    ece_main_kernel<<<GRID, TROWS, 0, stream>>>(logits, labels, gbins, n_rows);

    ece_final_kernel<<<1, 64, 0, stream>>>(gbins, out, 1.0f / (float)n_rows);
}